// Round 11
// baseline (266.795 us; speedup 1.0000x reference)
//
#include <hip/hip_runtime.h>
#include <math.h>

// Problem constants (NomicBertAttention): B=2, S=4096, DM=768, H=12, HD=64
#define B_   2
#define S_   4096
#define DM_  768
#define H_   12
#define HD_  64
#define M_   (B_ * S_)                 // 8192 rows
#define ROWELEMS ((size_t)M_ * DM_)    // 6291456 elems per [M,DM] buffer
#define WELEMS  ((size_t)DM_ * DM_)    // 589824 elems per weight

// net softmax scale: SCALING*SCALING = 1/64, times log2(e) so v_exp_f32 (2^x)
// computes e^(score/64) directly.  Folded into Q in the QKV-GEMM epilogue.
#define QSC (1.4426950408889634f / 64.0f)

typedef unsigned short u16;
typedef unsigned int   u32;
typedef __attribute__((ext_vector_type(8))) short  short8;   // 8 x bf16 (4 VGPR)
typedef __attribute__((ext_vector_type(4))) float  floatx4;  // MFMA accumulator
typedef __attribute__((ext_vector_type(4))) u32    uint32x4;

__device__ inline u16 f2bf(float f) {                 // RNE round
    u32 u = __builtin_bit_cast(u32, f);
    u += 0x7FFF + ((u >> 16) & 1);
    return (u16)(u >> 16);
}
__device__ inline float bf2f(u16 h) {
    return __builtin_bit_cast(float, (u32)h << 16);
}
__device__ inline u32 pk_trunc(float a, float b) {    // [bf16(b)<<16 | bf16(a)], truncate
    return __builtin_amdgcn_perm(__builtin_bit_cast(u32, b),
                                 __builtin_bit_cast(u32, a), 0x07060302);
}

// XOR-swizzled LDS offset, pitch 64 bf16 (128 B) rows:
// element (r, c) lives at r*64 + ((c/8 ^ (r&7))*8) + c%8.
__device__ inline int sw_off(int r, int cg) {         // cg = c>>3 (8-elem group)
    return (r << 6) + ((cg ^ (r & 7)) << 3);
}

// Async global->LDS 16B DMA (global_load_lds_dwordx4). LDS dest is
// wave-uniform base + lane*16; we permute the per-lane GLOBAL address so the
// content lands in the swizzled layout (same 128B lines -> still coalesced).
__device__ __forceinline__ void load_lds16(const u16* g, u16* l) {
    __builtin_amdgcn_global_load_lds(
        (const __attribute__((address_space(1))) u32*)g,
        (__attribute__((address_space(3))) u32*)l, 16, 0, 0);
}

// Explicit waitcnt encodings: simm16 = lgkmcnt<<8 | expcnt<<4 | vmcnt[3:0].
// R11 failed post-timing validation with a timing-dependent divergence; the
// DMA->barrier visibility must not depend on the compiler's barrier lowering
// emitting the vmcnt drain.  R12 proved the explicit drain; R19/R20 validated
// COUNTED vmcnt(4) across raw s_barriers on HW (passed, absmax unchanged).
// vmcnt drains oldest-first: "wait to <=N" always means "everything older
// than the newest N DMAs is done".
__device__ __forceinline__ void drain_vm() {
    __builtin_amdgcn_s_waitcnt(0x0F70);               // vmcnt(0)
}
__device__ __forceinline__ void wait_vm3() {
    __builtin_amdgcn_s_waitcnt(0x0F73);               // vmcnt(3)
}
__device__ __forceinline__ void wait_vm4() {
    __builtin_amdgcn_s_waitcnt(0x0F74);               // vmcnt(4)
}
__device__ __forceinline__ void wait_vm5() {
    __builtin_amdgcn_s_waitcnt(0x0F75);               // vmcnt(5)
}

// =====================================================================
// fp32 -> bf16 conversion: y=0 hidden [M,DM]; y=1..4 weights [DM,DM]
// =====================================================================
__global__ __launch_bounds__(256) void conv_bf16(
    const float* __restrict__ h,  const float* __restrict__ wq,
    const float* __restrict__ wk, const float* __restrict__ wv,
    const float* __restrict__ wo, u16* __restrict__ hb, u16* __restrict__ wb)
{
    const int y = blockIdx.y;
    const float* src; u16* dst; size_t n4;
    if (y == 0)      { src = h;  dst = hb;              n4 = ROWELEMS / 4; }
    else if (y == 1) { src = wq; dst = wb;              n4 = WELEMS / 4; }
    else if (y == 2) { src = wk; dst = wb + WELEMS;     n4 = WELEMS / 4; }
    else if (y == 3) { src = wv; dst = wb + 2 * WELEMS; n4 = WELEMS / 4; }
    else             { src = wo; dst = wb + 3 * WELEMS; n4 = WELEMS / 4; }
    const size_t stride = (size_t)gridDim.x * 256;
    for (size_t i = blockIdx.x * 256 + threadIdx.x; i < n4; i += stride) {
        float4 v = *(const float4*)&src[i * 4];
        u32 p0 = (u32)f2bf(v.x) | ((u32)f2bf(v.y) << 16);
        u32 p1 = (u32)f2bf(v.z) | ((u32)f2bf(v.w) << 16);
        *(uint2*)&dst[i * 4] = make_uint2(p0, p1);
    }
}

// =====================================================================
// Fused QKV GEMM + RoPE + head-major repack.
// R22 geometry kept: tile 128(m) x 192(n), grid (4, 64, 3) = 768 blocks
// = EXACTLY 3/CU (no schedule tail).  Waves: 4 along M, each wave
// 32 rows x 192 cols (acc[2][12]).
//
// R23: BK 64->32 with IN-PLACE double buffer (counted-vmcnt R19
// scheme) at ZERO LDS growth.  Trick: a [R][32] K-tile is stored as
// [R/2][64] -- two K=32 rows packed per 64-elem LDS row -- so the
// PROVEN sw_off layout applies verbatim.  Fragment read for global
// row r, k-group quad: sw_off(r>>1 + base, ((r&1)<<2)|quad).  The 16
// lanes hit each of the 8 slots exactly twice, at lrows 4 apart
// (512 B = same bank set) -> 2-way conflict = free (m136).
// Staging granule g: lrow = g>>3, cg = (g&7)^(lrow&7), global addr
// (2*lrow + (cg>>2))*LD + (cg&3)*8, LDS dest linear g*16B.
// Per tile: A 2 DMA/thread + W 3 DMA/thread = 5 -> vmcnt(5).
// Loop: STAGE(t+1 -> other buf) -> vmcnt(5) -> barrier -> COMPUTE(t)
// -> barrier.  24 tiles, prefetch always in flight across barriers
// (R19/R20 HW-validated).  LDS: As 2x8 KB + Ws 2x12 KB = 40 KB -> 3
// blocks/CU unchanged.
// Epilogue unchanged (acc layout identical to R22).
// =====================================================================
__global__ __launch_bounds__(256, 3) void gemm_qkv(
    const u16* __restrict__ A,
    const u16* __restrict__ W0, const u16* __restrict__ W1, const u16* __restrict__ W2,
    const float* __restrict__ b0, const float* __restrict__ b1, const float* __restrict__ b2,
    const float* __restrict__ cosT, const float* __restrict__ sinT,
    u16* __restrict__ Qh, u16* __restrict__ Kh, u16* __restrict__ Vt)
{
    __shared__ __align__(16) u16 As0[64 * 64];   // 8 KB: A[128][32] packed [64][64]
    __shared__ __align__(16) u16 As1[64 * 64];   // 8 KB (double buffer)
    __shared__ __align__(16) u16 Ws0[96 * 64];   // 12 KB: W[192][32] packed [96][64]
    __shared__ __align__(16) u16 Ws1[96 * 64];   // 12 KB

    const int tid  = threadIdx.x;
    const int wave = tid >> 6, lane = tid & 63;
    const int n16  = lane & 15, quad = lane >> 4;
    const int m0   = blockIdx.y * 128, n0 = blockIdx.x * 192;
    const int z    = blockIdx.z;

    const u16* Wz = (z == 0) ? W0 : (z == 1) ? W1 : W2;
    const float* bz = (z == 0) ? b0 : (z == 1) ? b1 : b2;

    // staging lane constants (packed-row granule -> global/LDS offsets)
    // A: 512 granules (2/thread); W: 768 granules (3/thread)
    int gao[2], ldsao[2], gwo[3], ldswo[3];
#pragma unroll
    for (int i = 0; i < 2; i++) {
        int g = wave * 128 + i * 64 + lane;      // 0..511
        int lr = g >> 3, cg = (g & 7) ^ (lr & 7);
        gao[i]   = (2 * lr + (cg >> 2)) * DM_ + (cg & 3) * 8;
        ldsao[i] = g * 8;
    }
#pragma unroll
    for (int i = 0; i < 3; i++) {
        int g = wave * 192 + i * 64 + lane;      // 0..767
        int lr = g >> 3, cg = (g & 7) ^ (lr & 7);
        gwo[i]   = (2 * lr + (cg >> 2)) * DM_ + (cg & 3) * 8;
        ldswo[i] = g * 8;
    }
    const u16* Ap = A  + (size_t)m0 * DM_;
    const u16* Wp = Wz + (size_t)n0 * DM_;

    floatx4 acc[2][12];
#pragma unroll
    for (int i = 0; i < 2; i++)
#pragma unroll
        for (int j = 0; j < 12; j++) acc[i][j] = (floatx4){0.f, 0.f, 0.f, 0.f};

    // fragment lane constants (packed rows): lrow = row>>1, cg = ((row&1)<<2)|quad
    const int afr = (n16 >> 1);                   // + wave*16 + t*8
    const int fcg = ((n16 & 1) << 2) | quad;

#define QSTAGE(K0, ADST, WDST)                                          \
    do {                                                                \
        _Pragma("unroll")                                               \
        for (int i_ = 0; i_ < 2; i_++)                                  \
            load_lds16(Ap + (K0) + gao[i_], &(ADST)[ldsao[i_]]);        \
        _Pragma("unroll")                                               \
        for (int i_ = 0; i_ < 3; i_++)                                  \
            load_lds16(Wp + (K0) + gwo[i_], &(WDST)[ldswo[i_]]);        \
    } while (0)

#define QCOMPUTE(ASB, WSB)                                              \
    do {                                                                \
        short8 af[2];                                                   \
        _Pragma("unroll")                                               \
        for (int t_ = 0; t_ < 2; t_++)                                  \
            af[t_] = *(const short8*)&(ASB)[sw_off(wave * 16 + t_ * 8 + afr, fcg)]; \
        _Pragma("unroll")                                               \
        for (int jh = 0; jh < 2; jh++) {                                \
            short8 bf[6];                                               \
            _Pragma("unroll")                                           \
            for (int j_ = 0; j_ < 6; j_++)                              \
                bf[j_] = *(const short8*)&(WSB)[sw_off((jh * 6 + j_) * 8 + afr, fcg)]; \
            _Pragma("unroll")                                           \
            for (int i_ = 0; i_ < 2; i_++)                              \
                _Pragma("unroll")                                       \
                for (int j_ = 0; j_ < 6; j_++)                          \
                    acc[i_][jh * 6 + j_] = __builtin_amdgcn_mfma_f32_16x16x32_bf16( \
                        af[i_], bf[j_], acc[i_][jh * 6 + j_], 0, 0, 0); \
        }                                                               \
    } while (0)

    // prologue: tile 0 -> buf0
    QSTAGE(0, As0, Ws0);

    for (int t = 0; t < 24; t += 2) {
        // half A: stage t+1 -> buf1, compute buf0
        QSTAGE((t + 1) * 32, As1, Ws1);
        wait_vm5();                               // tile t landed; t+1 in flight
        __syncthreads();
        QCOMPUTE(As0, Ws0);
        __syncthreads();                          // all waves done with buf0

        // half B: stage t+2 -> buf0, compute buf1
        if (t + 2 < 24) {
            QSTAGE((t + 2) * 32, As0, Ws0);
            wait_vm5();
        } else {
            drain_vm();
        }
        __syncthreads();
        QCOMPUTE(As1, Ws1);
        __syncthreads();                          // all waves done with buf1
    }
#undef QSTAGE
#undef QCOMPUTE

    // ---- epilogue: C/D layout col = n16, row = quad*4+r ----
    if (z == 2) {
#pragma unroll
        for (int i = 0; i < 2; i++)
#pragma unroll
            for (int j = 0; j < 12; j++) {
                const int col = n0 + j * 16 + n16;
                const int h = col >> 6, hd = col & 63;
                const int row0 = m0 + wave * 32 + i * 16 + quad * 4;
                const int b = row0 >> 12, s0 = row0 & 4095;
                const float bias = bz[col];
                float v0 = acc[i][j][0] + bias, v1 = acc[i][j][1] + bias;
                float v2 = acc[i][j][2] + bias, v3 = acc[i][j][3] + bias;
                u32 w0 = (u32)f2bf(v0) | ((u32)f2bf(v1) << 16);
                u32 w1 = (u32)f2bf(v2) | ((u32)f2bf(v3) << 16);
                *(uint2*)&Vt[((size_t)(b * H_ + h) * HD_ + hd) * S_ + s0] = make_uint2(w0, w1);
            }
    } else {
        u32* Out32 = (u32*)((z == 0) ? Qh : Kh);
        const float sc_ = (z == 0) ? QSC : 1.0f;
#pragma unroll
        for (int i = 0; i < 2; i++)
#pragma unroll
            for (int jp = 0; jp < 6; jp++) {
                const int j1 = (jp >> 1) * 4 + (jp & 1);   // {0,1,4,5,8,9}: x1 tiles
                const int col1 = n0 + j1 * 16 + n16;
                const int h = col1 >> 6, hd1 = col1 & 63;  // hd1 in [0,32)
                const float bias1 = bz[col1], bias2 = bz[col1 + 32];
#pragma unroll
                for (int r = 0; r < 4; r++) {
                    const int row = m0 + wave * 32 + i * 16 + quad * 4 + r;
                    const int b = row >> 12, s = row & 4095;
                    const float c  = cosT[s * HD_ + hd1];
                    const float sn = sinT[s * HD_ + hd1];
                    const float x1 = acc[i][j1][r] + bias1;
                    const float x2 = acc[i][j1 + 2][r] + bias2;
                    const float y1 = (x1 * c - x2 * sn) * sc_;
                    const float y2 = (x2 * c + x1 * sn) * sc_;
                    // pair-interleaved: u32 slot hd1 of the 32-u32 row
                    Out32[(((size_t)(b * H_ + h) * S_ + s) << 5) + hd1] =
                        (u32)f2bf(y1) | ((u32)f2bf(y2) << 16);
                }
            }
    }
}

// =====================================================================
// Flash attention, bf16 MFMA, static softmax.
// grid (S/128, B*H) = 768 blocks = 3/CU; 64 K-tiles/block; 4 waves,
// each wave owns 32 q-rows (rt=2) -- the R17 shape.
//
// R20 structure (FINAL): SINGLE BARRIER PER TILE via TRIPLE BUFFER.
// Per tile: vmcnt(4) [tile t landed, t+1 in flight] -> s_barrier ->
// STAGE(t+2 into buf (t+2)%3, which the barrier just certified free)
// -> COMPUTE(t).  Buffer names STATIC (rule #20).  64 sync points.
// R21's setprio was NULL -> reverted.  All pipes sub-saturated
// (MfmaUtil ~50, VALU ~46, LDS ~57) -> dependency-overlap bound; R18
// proved rt=4 trades occupancy at a loss, R19 proved DMA latency is
// covered.  Declared done at this structure.
//
// rho row-permutation + in-register pa packing carried from R17:
// K staged with row shuffle rho (bits b4<-b3, b3<-b2, b2<-b4), so
// lane (n16,quad)'s S^T values ARE its PV A-fragment:
// pa[rt][ks] = {pk(sct[2ks][rt]), pk(sct[2ks+1][rt])}.  No Ps LDS.
//
// __launch_bounds__(256,3): VGPR cap 168 (alloc 84).  LDS 48 KB ->
// 3 blocks/CU.  DO NOT raise to (256,5): R10 -> forced spill.
// =====================================================================
__global__ __launch_bounds__(256, 3) void flash_mfma(
    const u16* __restrict__ Qh, const u16* __restrict__ Kh,
    const u16* __restrict__ Vt, u16* __restrict__ O)
{
    __shared__ __align__(16) u16 Ks0[64 * 64];    // 8 KB  K[named kcol][d], rho-permuted
    __shared__ __align__(16) u16 Vs0[64 * 64];    // 8 KB  V^T[d][kcol]
    __shared__ __align__(16) u16 Ks1[64 * 64];    // 8 KB  (triple buffer)
    __shared__ __align__(16) u16 Vs1[64 * 64];    // 8 KB
    __shared__ __align__(16) u16 Ks2[64 * 64];    // 8 KB
    __shared__ __align__(16) u16 Vs2[64 * 64];    // 8 KB

    const int tid  = threadIdx.x;
    const int wave = tid >> 6, lane = tid & 63;
    const int n16  = lane & 15, quad = lane >> 4;
    const int qt   = blockIdx.x;
    const int bh   = blockIdx.y;
    const size_t qk_base = (size_t)bh * S_ * HD_;
    const size_t vt_base = (size_t)bh * HD_ * S_;
    const int q0   = qt * 128;
    const int wrow = wave * 32;

    // Q fragments in registers (A/B frag layout: lane&15 x (quad*8+j))
    short8 qf[2][2];
#pragma unroll
    for (int rt = 0; rt < 2; rt++)
#pragma unroll
        for (int ks = 0; ks < 2; ks++)
            qf[rt][ks] = *(const short8*)&Qh[qk_base +
                (size_t)(q0 + wrow + rt * 16 + n16) * HD_ + ks * 32 + quad * 8];

    short8 ones;
#pragma unroll
    for (int j = 0; j < 8; j++) ones[j] = (short)0x3F80;   // bf16 1.0

    // staging lane constants (swizzled global addresses).
    // K rows permuted by rho: LDS named row n holds physical K row rho(n).
    int gk_off[2], gv_off[2], ldso[2];
#pragma unroll
    for (int i = 0; i < 2; i++) {
        int g = wave * 128 + i * 64 + lane;       // 0..511
        int r = g >> 3, cg = (g & 7) ^ (r & 7);
        int rk = (r & 0x23) | ((r & 8) << 1) | ((r & 4) << 1) | ((r & 16) >> 2);
        gk_off[i] = rk * HD_ + cg * 8;
        gv_off[i] = r  * S_  + cg * 8;
        ldso[i]   = (wave * 128 + i * 64) * 8;
    }

    floatx4 o_acc[2][4];
    floatx4 o_l[2];                   // l accumulator (ones-MFMA, C-layout)
#pragma unroll
    for (int rt = 0; rt < 2; rt++) {
        o_l[rt] = (floatx4){0.f, 0.f, 0.f, 0.f};
#pragma unroll
        for (int dt = 0; dt < 4; dt++) o_acc[rt][dt] = (floatx4){0.f, 0.f, 0.f, 0.f};
    }

    const u16* Kg = Kh + qk_base;
    const u16* Vg = Vt + vt_base;
#define KT (64 * HD_)

// stage one 64-kcol tile: 2 K DMAs + 2 V DMAs per wave (4 total)
#define STAGE(KSRC, VSRC, KDST, VDST)                                   \
    do {                                                                \
        _Pragma("unroll")                                               \
        for (int i_ = 0; i_ < 2; i_++) {                                \
            load_lds16((KSRC) + gk_off[i_], &(KDST)[ldso[i_]]);         \
            load_lds16((VSRC) + gv_off[i_], &(VDST)[ldso[i_]]);         \
        }                                                               \
    } while (0)

// R17 compute body on one tile (16 ds_read_b128, 36 MFMA, in-reg pa)
#define COMPUTE_TILE(KSB, VSB)                                          \
    do {                                                                \
        floatx4 sct[4][2];                                              \
        _Pragma("unroll")                                               \
        for (int ct = 0; ct < 4; ct++)                                  \
            _Pragma("unroll")                                           \
            for (int rt = 0; rt < 2; rt++)                              \
                sct[ct][rt] = (floatx4){0.f, 0.f, 0.f, 0.f};            \
        _Pragma("unroll")                                               \
        for (int ks = 0; ks < 2; ks++) {                                \
            short8 kf[4];                                               \
            _Pragma("unroll")                                           \
            for (int ct = 0; ct < 4; ct++)                              \
                kf[ct] = *(const short8*)&(KSB)[sw_off(ct * 16 + n16,   \
                                                       ks * 4 + quad)]; \
            _Pragma("unroll")                                           \
            for (int ct = 0; ct < 4; ct++)                              \
                _Pragma("unroll")                                       \
                for (int rt = 0; rt < 2; rt++)                          \
                    sct[ct][rt] = __builtin_amdgcn_mfma_f32_16x16x32_bf16( \
                        kf[ct], qf[rt][ks], sct[ct][rt], 0, 0, 0);      \
        }                                                               \
        short8 pa[2][2];                                                \
        _Pragma("unroll")                                               \
        for (int rt = 0; rt < 2; rt++)                                  \
            _Pragma("unroll")                                           \
            for (int ks = 0; ks < 2; ks++) {                            \
                const floatx4 lo = sct[2 * ks][rt];                     \
                const floatx4 hi = sct[2 * ks + 1][rt];                 \
                uint32x4 w;                                             \
                w[0] = pk_trunc(__builtin_amdgcn_exp2f(lo[0]),          \
                                __builtin_amdgcn_exp2f(lo[1]));         \
                w[1] = pk_trunc(__builtin_amdgcn_exp2f(lo[2]),          \
                                __builtin_amdgcn_exp2f(lo[3]));         \
                w[2] = pk_trunc(__builtin_amdgcn_exp2f(hi[0]),          \
                                __builtin_amdgcn_exp2f(hi[1]));         \
                w[3] = pk_trunc(__builtin_amdgcn_exp2f(hi[2]),          \
                                __builtin_amdgcn_exp2f(hi[3]));         \
                pa[rt][ks] = __builtin_bit_cast(short8, w);             \
            }                                                           \
        _Pragma("unroll")                                               \
        for (int ks = 0; ks < 2; ks++) {                                \
            short8 vb[4];                                               \
            _Pragma("unroll")                                           \
            for (int dt = 0; dt < 4; dt++)                              \
                vb[dt] = *(const short8*)&(VSB)[sw_off(dt * 16 + n16,   \
                                                       ks * 4 + quad)]; \
            _Pragma("unroll")                                           \
            for (int rt = 0; rt < 2; rt++) {                            \
                _Pragma("unroll")                                       \
                for (int dt = 0; dt < 4; dt++)                          \
                    o_acc[rt][dt] = __builtin_amdgcn_mfma_f32_16x16x32_bf16( \
                        pa[rt][ks], vb[dt], o_acc[rt][dt], 0, 0, 0);    \
                o_l[rt] = __builtin_amdgcn_mfma_f32_16x16x32_bf16(      \
                    pa[rt][ks], ones, o_l[rt], 0, 0, 0);                \
            }                                                           \
        }                                                               \
    } while (0)

    // ---- prologue: tiles 0,1 -> buffers 0,1 ----
    STAGE(Kg,      Vg,      Ks0, Vs0);
    STAGE(Kg + KT, Vg + 64, Ks1, Vs1);

    // t = 3g+p computes buf p%3 and stages t+2 -> buf (t+2)%3.
    // 21 groups cover t = 0..62; tile 63 handled in the epilogue iter.
    for (int g = 0; g < 21; ++g) {
        // -- t = 3g: compute b0, stage t+2 -> b2 --
        wait_vm4();                               // tile t landed; t+1 in flight
        __builtin_amdgcn_s_barrier();             // t visible; compute(t-1) done by ALL
        STAGE(Kg + 2 * KT, Vg + 2 * 64, Ks2, Vs2);
        COMPUTE_TILE(Ks0, Vs0);
        Kg += KT; Vg += 64;

        // -- t = 3g+1: compute b1, stage t+2 -> b0 --
        wait_vm4();
        __builtin_amdgcn_s_barrier();
        STAGE(Kg + 2 * KT, Vg + 2 * 64, Ks0, Vs0);
        COMPUTE_TILE(Ks1, Vs1);
        Kg += KT; Vg += 64;

        // -- t = 3g+2: compute b2, stage t+2 -> b1 (except t=62: t+2=64) --
        wait_vm4();
        __builtin_amdgcn_s_barrier();
        if (g < 20)
            STAGE(Kg + 2 * KT, Vg + 2 * 64, Ks1, Vs1);
        COMPUTE_TILE(Ks2, Vs2);
        Kg += KT; Vg += 64;
    }
    // -- t = 63: compute b0 (staged at t=61) --
    drain_vm();                                   // last tile fully landed
    __builtin_amdgcn_s_barrier();
    COMPUTE_TILE(Ks0, Vs0);
#undef STAGE
#undef COMPUTE_TILE
#undef KT

    // ---- epilogue: normalize by complete l (C-layout: row=quad*4+r, all
    // cols equal, so every lane holds its row's l) and write final bf16 O ----
    const int b = bh / H_, h = bh % H_;
#pragma unroll
    for (int rt = 0; rt < 2; rt++)
#pragma unroll
        for (int r = 0; r < 4; r++) {
            const float inv = 1.0f / o_l[rt][r];
            const int srow = q0 + wrow + rt * 16 + quad * 4 + r;
            u16* Orow = O + ((size_t)b * S_ + srow) * DM_ + h * HD_;
#pragma unroll
            for (int dt = 0; dt < 4; dt++)
                Orow[dt * 16 + n16] = f2bf(o_acc[rt][dt][r] * inv);
        }
}

// =====================================================================
// Out-proj GEMM: out = A @ Wo^T + hidden (fp32).
// Tile 64(m) x 128(n), 2x2 waves (wave: 32 rows x 64 cols).
// R23: BK 64->32 in-place double buffer, same packed-row layout as
// gemm_qkv (A[64][32] -> [32][64], W[128][32] -> [64][64]).  Per tile:
// A 1 + W 2 = 3 DMA/thread -> vmcnt(3).  LDS 24 KB unchanged -> 4
// blocks/CU kept.  24 tiles, counted-vmcnt prefetch (R19 scheme).
// =====================================================================
__global__ __launch_bounds__(256, 4) void gemm_out(
    const u16* __restrict__ A, const u16* __restrict__ W,
    const float* __restrict__ resid, float* __restrict__ Cf)
{
    __shared__ __align__(16) u16 As0[32 * 64];    // 4 KB
    __shared__ __align__(16) u16 As1[32 * 64];    // 4 KB
    __shared__ __align__(16) u16 Ws0[64 * 64];    // 8 KB
    __shared__ __align__(16) u16 Ws1[64 * 64];    // 8 KB

    const int tid  = threadIdx.x;
    const int wave = tid >> 6, lane = tid & 63;
    const int n16  = lane & 15, quad = lane >> 4;
    const int wm   = wave >> 1, wn = wave & 1;
    const int m0   = blockIdx.y * 64, n0 = blockIdx.x * 128;

    // staging lane constants (packed-row granules)
    int gao, ldsao, gwo[2], ldswo[2];
    {
        int g = wave * 64 + lane;                 // A: 256 granules, 1/thread
        int lr = g >> 3, cg = (g & 7) ^ (lr & 7);
        gao   = (2 * lr + (cg >> 2)) * DM_ + (cg & 3) * 8;
        ldsao = g * 8;
    }
#pragma unroll
    for (int i = 0; i < 2; i++) {                 // W: 512 granules, 2/thread
        int g = wave * 128 + i * 64 + lane;
        int lr = g >> 3, cg = (g & 7) ^ (lr & 7);
        gwo[i]   = (2 * lr + (cg >> 2)) * DM_ + (cg & 3) * 8;
        ldswo[i] = g * 8;
    }
    const u16* Wp = W + (size_t)n0 * DM_;
    const u16* Ap = A + (size_t)m0 * DM_;

    floatx4 acc[2][4];
#pragma unroll
    for (int i = 0; i < 2; i++)
#pragma unroll
        for (int j = 0; j < 4; j++) acc[i][j] = (floatx4){0.f, 0.f, 0.f, 0.f};

    const int afr = (n16 >> 1);
    const int fcg = ((n16 & 1) << 2) | quad;

#define OSTAGE(K0, ADST, WDST)                                          \
    do {                                                                \
        load_lds16(Ap + (K0) + gao, &(ADST)[ldsao]);                    \
        _Pragma("unroll")                                               \
        for (int i_ = 0; i_ < 2; i_++)                                  \
            load_lds16(Wp + (K0) + gwo[i_], &(WDST)[ldswo[i_]]);        \
    } while (0)

#define OCOMPUTE(ASB, WSB)                                              \
    do {                                                                \
        short8 af[2], bf[4];                                            \
        _Pragma("unroll")                                               \
        for (int rt = 0; rt < 2; rt++)                                  \
            af[rt] = *(const short8*)&(ASB)[sw_off(wm * 16 + rt * 8 + afr, fcg)]; \
        _Pragma("unroll")                                               \
        for (int ct = 0; ct < 4; ct++)                                  \
            bf[ct] = *(const short8*)&(WSB)[sw_off(wn * 32 + ct * 8 + afr, fcg)]; \
        _Pragma("unroll")                                               \
        for (int rt = 0; rt < 2; rt++)                                  \
            _Pragma("unroll")                                           \
            for (int ct = 0; ct < 4; ct++)                              \
                acc[rt][ct] = __builtin_amdgcn_mfma_f32_16x16x32_bf16(  \
                    af[rt], bf[ct], acc[rt][ct], 0, 0, 0);              \
    } while (0)

    OSTAGE(0, As0, Ws0);

    for (int t = 0; t < 24; t += 2) {
        OSTAGE((t + 1) * 32, As1, Ws1);
        wait_vm3();                               // tile t landed; t+1 in flight
        __syncthreads();
        OCOMPUTE(As0, Ws0);
        __syncthreads();

        if (t + 2 < 24) {
            OSTAGE((t + 2) * 32, As0, Ws0);
            wait_vm3();
        } else {
            drain_vm();
        }
        __syncthreads();
        OCOMPUTE(As1, Ws1);
        __syncthreads();
    }
#undef OSTAGE
#undef OCOMPUTE

#pragma unroll
    for (int rt = 0; rt < 2; rt++)
#pragma unroll
        for (int ct = 0; ct < 4; ct++) {
            const int col = n0 + wn * 64 + ct * 16 + n16;
#pragma unroll
            for (int r = 0; r < 4; r++) {
                const int row = m0 + wm * 32 + rt * 16 + quad * 4 + r;
                Cf[(size_t)row * DM_ + col] = acc[rt][ct][r] + resid[(size_t)row * DM_ + col];
            }
        }
}

// =====================================================================
// LayerNorm in-place on [M, DM] rows. grid: M, block: 256 (R12-proven)
// =====================================================================
__global__ __launch_bounds__(256) void ln_kernel(
    float* __restrict__ io, const float* __restrict__ g, const float* __restrict__ bb)
{
    const int row = blockIdx.x, t = threadIdx.x;
    float* p = io + (size_t)row * DM_;
    float x[3];
    float sum = 0.0f, sq = 0.0f;
#pragma unroll
    for (int i = 0; i < 3; i++) {
        x[i] = p[t + i * 256];
        sum += x[i];
        sq  = fmaf(x[i], x[i], sq);
    }
#pragma unroll
    for (int off = 32; off >= 1; off >>= 1) {
        sum += __shfl_xor(sum, off);
        sq  += __shfl_xor(sq, off);
    }
    __shared__ float s1[4], s2[4];
    if ((t & 63) == 0) { s1[t >> 6] = sum; s2[t >> 6] = sq; }
    __syncthreads();
    sum = s1[0] + s1[1] + s1[2] + s1[3];
    sq  = s2[0] + s2[1] + s2[2] + s2[3];
    const float mu  = sum * (1.0f / 768.0f);
    const float var = sq * (1.0f / 768.0f) - mu * mu;
    const float rs  = rsqrtf(var + 1e-12f);
#pragma unroll
    for (int i = 0; i < 3; i++) {
        const int c = t + i * 256;
        p[c] = (x[i] - mu) * rs * g[c] + bb[c];
    }
}

// =====================================================================
// Workspace (bf16 elem offsets; total ~55.5 MB <= proven 75.5 MB):
//   Hb [0,R)      -> O (final attn out, bf16) overlays after gemm_qkv
//   Wb [R, R+4W)
//   Qh, Kh, Vt    (R each)
// =====================================================================
extern "C" void kernel_launch(void* const* d_in, const int* in_sizes, int n_in,
                              void* d_out, int out_size, void* d_ws, size_t ws_size,
                              hipStream_t stream)
{
    const float* hidden = (const float*)d_in[0];
    const float* cosT   = (const float*)d_in[1];
    const float* sinT   = (const float*)d_in[2];
    const float* Wq     = (const float*)d_in[3];
    const float* bq     = (const float*)d_in[4];
    const float* Wk     = (const float*)d_in[5];
    const float* bk     = (const float*)d_in[6];
    const float* Wv     = (const float*)d_in[7];
    const float* bv     = (const float*)d_in[8];
    const float* Wo     = (const float*)d_in[9];
    const float* ln_g   = (const float*)d_in[10];
    const float* ln_b   = (const float*)d_in[11];
    float* out = (float*)d_out;

    u16* wsb = (u16*)d_ws;
    u16* Hb  = wsb;
    u16* Wb  = wsb + ROWELEMS;
    u16* Qh  = Wb + 4 * WELEMS;
    u16* Kh  = Qh + ROWELEMS;
    u16* Vt  = Kh + ROWELEMS;
    u16* Ob  = Hb;                        // overlays Hb (dead after gemm_qkv)
    u16* Wqb = Wb, *Wkb = Wb + WELEMS, *Wvb = Wb + 2 * WELEMS, *Wob = Wb + 3 * WELEMS;

    conv_bf16<<<dim3(1024, 5), 256, 0, stream>>>(hidden, Wq, Wk, Wv, Wo, Hb, Wb);

    gemm_qkv<<<dim3(DM_ / 192, M_ / 128, 3), 256, 0, stream>>>(
        Hb, Wqb, Wkb, Wvb, bq, bk, bv, cosT, sinT, Qh, Kh, Vt);

    flash_mfma<<<dim3(S_ / 128, B_ * H_), 256, 0, stream>>>(Qh, Kh, Vt, Ob);

    gemm_out<<<dim3(DM_ / 128, M_ / 64), 256, 0, stream>>>(Ob, Wob, hidden, out);

    ln_kernel<<<M_, 256, 0, stream>>>(out, ln_g, ln_b);
}